// Round 6
// baseline (115725.171 us; speedup 1.0000x reference)
//
#include <hip/hip_runtime.h>
#include <cstdint>

#define TPB 256
#define GRID_WGS 256

// problem dims
#define NB    32
#define TIN   400
#define TOUT  500
#define NMEL  80
#define EDIM  512
#define ARNN  1024
#define PDIM  256
#define ADIM  128
#define NGATE 4096

#define KSA 7        // attention-LSTM K = 1792 = 7 x 256
#define KSD 8        // decoder-LSTM   K = 2560 = 8 x 320
#define NTASK_A 112  // 16 j-tiles x 7 k-chunks
#define NTASK   240  // + 16 j-tiles x 8 k-chunks  -> <=1 task per WG (balanced)

// double-region offsets (units: doubles)
#define PM_OFF   0          // pmT[b][a][t] [32][128][400]
#define WFC_OFF  1638400    // [128][62]
#define AH_OFF   1646336
#define AC_OFF   1679104
#define DH_OFF   1711872
#define DC_OFF   1744640
#define CTX_OFF  1777408
#define AW_OFF   1793792
#define AWC_OFF  1806592
#define EN_OFF   1819392
#define PQ_OFF   1832192
#define PRE0_OFF 1836288
#define PRE1_OFF 1844480
#define DBL_END  1852672
// float region (units: floats, base = (float*)(ws + DBL_END))
#define PAF_OFF  0          // A partials [7][32][4096]
#define PDF_OFF  917504     // D partials [8][32][4096]
#define F_END    1966080
// barrier region after float region: flags[256] (4B each) + gen at its own line
#define BAR_UINTS 320       // 1280 B: flags[0..255], gen at [256]
#define GEN_IDX   256
#define WS_BYTES ((size_t)DBL_END*8 + (size_t)F_END*4 + (size_t)BAR_UINTS*4)

#define MEL_OFF  0
#define GATE_OFF 1280000
#define AL_OFF   1296000

// ---------------- agent-coherent (sc1, coherence-point) access wrappers ----------------
__device__ __forceinline__ double ld_d(const double* p){
  return __hip_atomic_load(p, __ATOMIC_RELAXED, __HIP_MEMORY_SCOPE_AGENT);
}
__device__ __forceinline__ void st_d(double* p, double v){
  __hip_atomic_store(p, v, __ATOMIC_RELAXED, __HIP_MEMORY_SCOPE_AGENT);
}
__device__ __forceinline__ float ld_f(const float* p){
  return __hip_atomic_load(p, __ATOMIC_RELAXED, __HIP_MEMORY_SCOPE_AGENT);
}
__device__ __forceinline__ void st_f(float* p, float v){
  __hip_atomic_store(p, v, __ATOMIC_RELAXED, __HIP_MEMORY_SCOPE_AGENT);
}

// ---------------- flag-array grid barrier (round-3/5-proven form, all relaxed) ---------
__device__ __forceinline__ void gridbar(unsigned* flags, unsigned* gen, int wg, int tid, unsigned g){
  __syncthreads();
  if (tid == 0){
    asm volatile("s_waitcnt vmcnt(0) lgkmcnt(0)" ::: "memory");
    __hip_atomic_store(flags + wg, g, __ATOMIC_RELAXED, __HIP_MEMORY_SCOPE_AGENT);
  }
  if (wg == 0){
    while (__hip_atomic_load(flags + tid, __ATOMIC_RELAXED, __HIP_MEMORY_SCOPE_AGENT) < g)
      __builtin_amdgcn_s_sleep(1);
    __syncthreads();
    if (tid == 0)
      __hip_atomic_store(gen, g, __ATOMIC_RELAXED, __HIP_MEMORY_SCOPE_AGENT);
  } else {
    if (tid == 0){
      while (__hip_atomic_load(gen, __ATOMIC_RELAXED, __HIP_MEMORY_SCOPE_AGENT) < g)
        __builtin_amdgcn_s_sleep(1);
    }
  }
  __syncthreads();
}

// ---------------- threefry2x32 core (bit-exact JAX) ----------------
__device__ __forceinline__ uint32_t rotl32(uint32_t v, int r){ return (v<<r)|(v>>(32-r)); }

__device__ __forceinline__ void tf_block(uint32_t k0, uint32_t k1, uint32_t x0, uint32_t x1,
                                         uint32_t& y0, uint32_t& y1){
  uint32_t k2 = k0 ^ k1 ^ 0x1BD11BDAu;
  x0 += k0; x1 += k1;
#define TF4(r0,r1,r2,r3,ka,kb,inc) \
  x0 += x1; x1 = rotl32(x1,r0); x1 ^= x0; \
  x0 += x1; x1 = rotl32(x1,r1); x1 ^= x0; \
  x0 += x1; x1 = rotl32(x1,r2); x1 ^= x0; \
  x0 += x1; x1 = rotl32(x1,r3); x1 ^= x0; \
  x0 += (ka); x1 += (kb) + (inc);
  TF4(13,15,26,6,  k1,k2,1u)
  TF4(17,29,16,24, k2,k0,2u)
  TF4(13,15,26,6,  k0,k1,3u)
  TF4(17,29,16,24, k1,k2,4u)
  TF4(13,15,26,6,  k2,k0,5u)
#undef TF4
  y0 = x0; y1 = x1;
}

__device__ __forceinline__ bool tf_keep_part(uint32_t k0, uint32_t k1, uint32_t i){
  uint32_t y0, y1;
  tf_block(k0, k1, 0u, i, y0, y1);
  return (((y0 ^ y1) >> 31) == 0u);
}

// ---------------- precompute kernels (fp64) ----------------
__global__ __launch_bounds__(TPB) void pm_kernel(
    const float* __restrict__ memory, const float* __restrict__ Wm, double* __restrict__ pmT)
{
  const int bt = blockIdx.x;           // b*400 + t
  const int b = bt / TIN, t2 = bt - b*TIN;
  const int tid = threadIdx.x;
  __shared__ double sm[EDIM];
  __shared__ double sp[TPB];
  for (int i = tid; i < EDIM; i += TPB) sm[i] = (double)memory[(size_t)bt*EDIM + i];
  __syncthreads();
  const int a = tid & 127, hf = tid >> 7;
  const float* w = Wm + (size_t)a*EDIM + hf*256;
  const double* x = sm + hf*256;
  double s = 0.0;
  for (int e = 0; e < 256; ++e) s += (double)w[e]*x[e];
  sp[tid] = s;
  __syncthreads();
  if (tid < ADIM) pmT[((size_t)b*ADIM + tid)*TIN + t2] = sp[tid] + sp[tid+128];
}

__global__ __launch_bounds__(TPB) void wfc_kernel(
    const float* __restrict__ Wd, const float* __restrict__ Wc, double* __restrict__ wfc)
{
  for (int o = threadIdx.x; o < ADIM*62; o += TPB){
    int a = o / 62, ck = o - a*62;
    double s = 0.0;
    for (int f = 0; f < 32; ++f) s += (double)Wd[a*32+f]*(double)Wc[f*62 + ck];
    wfc[o] = s;
  }
}

__global__ void bar_init_kernel(unsigned* bar){
  for (int i = threadIdx.x; i < BAR_UINTS; i += blockDim.x) bar[i] = 0u;
}
__global__ void sentinel_kernel(float* out, float val){ out[0] = val; }

// ---------------- main persistent kernel ----------------
struct DecParams {
  const float *memory, *dec;
  const float *Wpre1, *Wpre2;
  const float *WihA,*WhhA,*bihA,*bhhA;
  const float *Wq,*v;
  const float *WihD,*WhhD,*bihD,*bhhD;
  const float *Wp,*bp,*Wg,*bg;
  const unsigned char* mask;
  double* ws;
  float* out;
};

__device__ __forceinline__ double sigd(double x){ return 1.0/(1.0+exp(-x)); }

// 4 outputs x 8 k fp64 FMA block (w?? scalars must be in scope)
#define ROWFMA(a0,a1,a2,a3, xp) do{ \
  const double x0=(xp)[0],x1=(xp)[1],x2=(xp)[2],x3=(xp)[3], \
               x4=(xp)[4],x5=(xp)[5],x6=(xp)[6],x7=(xp)[7]; \
  a0 += w00*x0+w01*x1+w02*x2+w03*x3+w04*x4+w05*x5+w06*x6+w07*x7; \
  a1 += w10*x0+w11*x1+w12*x2+w13*x3+w14*x4+w15*x5+w16*x6+w17*x7; \
  a2 += w20*x0+w21*x1+w22*x2+w23*x3+w24*x4+w25*x5+w26*x6+w27*x7; \
  a3 += w30*x0+w31*x1+w32*x2+w33*x3+w34*x4+w35*x5+w36*x6+w37*x7; \
}while(0)

__global__ __launch_bounds__(TPB, 1) void decoder_main(DecParams P)
{
  const int wg = blockIdx.x, tid = threadIdx.x;
  const int nwg = GRID_WGS;
  // LDS: sb (max non-PH1 use = 1856 doubles) + W chunk tile [256][33] fp32 = 50176 B
  __shared__ __align__(16) double sb[2048];     // 16 KB; PH1 uses first 1024 as X tile
  __shared__ __align__(16) float  wlds[8448];   // 33 KB; 256 rows x stride 33

  double* ws  = P.ws;
  double* pmT = ws + PM_OFF;   double* wfc = ws + WFC_OFF;
  double* ah  = ws + AH_OFF;   double* ac  = ws + AC_OFF;
  double* dh  = ws + DH_OFF;   double* dc  = ws + DC_OFF;
  double* ctx = ws + CTX_OFF;  double* aw  = ws + AW_OFF;  double* awc = ws + AWC_OFF;
  double* en  = ws + EN_OFF;   double* pq  = ws + PQ_OFF;
  float*  pAf = (float*)(ws + DBL_END);
  float*  pDf = pAf + PDF_OFF;
  unsigned* flags = (unsigned*)(pAf + F_END);
  unsigned* gen   = flags + GEN_IDX;
  unsigned g = 0;

  // zero recurrent state + pre buffers via sc1 stores
  for (int i = wg*TPB + tid; i < DBL_END - AH_OFF; i += nwg*TPB) st_d(ah + i, 0.0);
  gridbar(flags, gen, wg, tid, ++g);

  #pragma unroll 1
  for (int t = 0; t <= TOUT; ++t){
    const double* pre_cur = ws + ((t & 1) ? PRE1_OFF : PRE0_OFF);

    // ---- PH1: fp64 gate-GEMM partials, LDS-staged coalesced weights ----
    // Lane jg owns rows {jg, 64+jg, 128+jg, 192+jg} of the 256-row j-tile.
    if (wg < NTASK){
      const bool isA = wg < NTASK_A;
      if (isA ? (t < TOUT) : (t > 0)){
        int jt, ks, kbase, kspan;
        if (isA){ jt = wg / KSA; ks = wg - jt*KSA; kbase = ks*256; kspan = 256; }
        else    { int r = wg - NTASK_A; jt = r >> 3; ks = r & 7; kbase = ks*320; kspan = 320; }
        const int jg = tid & 63, bgi = tid >> 6;
        const int wrow = tid >> 3;         // 0..31: row-within-32-group for coop load
        const int wk4  = (tid & 7) << 2;   // 0,4,...,28: k-offset (float4) for coop load
        double acc[32];
        #pragma unroll
        for (int i = 0; i < 32; ++i) acc[i] = 0.0;

        // chunks of 32 k; no chunk straddles an input-segment or ih/hh boundary
        // (all boundaries 256/768/1024/1536 and kbase/kspan are multiples of 32)
        #pragma unroll 1
        for (int kc = 0; kc < kspan; kc += 32){
          const int kg0 = kbase + kc;
          // stage X[32 b][32 k] (sc1 state reads), 4 elems/thread
          #pragma unroll
          for (int q = 0; q < 4; ++q){
            const int i = tid + q*256;            // 0..1023
            const int b = i >> 5, kloc = i & 31, kg = kg0 + kloc;
            double xv;
            if (isA){
              if (kg < 256)       xv = ld_d(pre_cur + (b<<8) + kg);
              else if (kg < 768)  xv = ld_d(ctx + b*EDIM + (kg-256));
              else                xv = ld_d(ah + b*ARNN + (kg-768));
            } else {
              if (kg < 1024)      xv = ld_d(ah + b*ARNN + kg);
              else if (kg < 1536) xv = ld_d(ctx + b*EDIM + (kg-1024));
              else                xv = ld_d(dh + b*ARNN + (kg-1536));
            }
            sb[(b<<5) + kloc] = xv;
          }
          // cooperative coalesced W chunk load: [256 rows][32 k] -> wlds[row*33+k]
          // 8 lanes x float4 = one full 128B row-segment; each wave-inst = 8 whole lines
          const float* wbase; int rowlen, koff;
          if (isA){
            if (kg0 < 768){ wbase = P.WihA; rowlen = 768;  koff = kg0; }
            else          { wbase = P.WhhA; rowlen = 1024; koff = kg0-768; }
          } else {
            if (kg0 < 1536){ wbase = P.WihD; rowlen = 1536; koff = kg0; }
            else           { wbase = P.WhhD; rowlen = 1024; koff = kg0-1536; }
          }
          const float* wt = wbase + (size_t)(jt*256 + wrow)*rowlen + koff + wk4;
          #pragma unroll
          for (int i2 = 0; i2 < 8; ++i2){
            const float4 wv4 = *(const float4*)(wt + (size_t)(i2*32)*rowlen);
            float* p = wlds + (i2*32 + wrow)*33 + wk4;
            p[0]=wv4.x; p[1]=wv4.y; p[2]=wv4.z; p[3]=wv4.w;
          }
          __syncthreads();
          // FMA: 4 sub-blocks of 8 k; w from LDS (2-way bank = free), x broadcast
          #pragma unroll 1
          for (int kk = 0; kk < 32; kk += 8){
            const float* wl0 = wlds + ( 0 + jg)*33 + kk;
            const float* wl1 = wlds + ( 64 + jg)*33 + kk;
            const float* wl2 = wlds + (128 + jg)*33 + kk;
            const float* wl3 = wlds + (192 + jg)*33 + kk;
            const double w00=wl0[0],w01=wl0[1],w02=wl0[2],w03=wl0[3],
                         w04=wl0[4],w05=wl0[5],w06=wl0[6],w07=wl0[7];
            const double w10=wl1[0],w11=wl1[1],w12=wl1[2],w13=wl1[3],
                         w14=wl1[4],w15=wl1[5],w16=wl1[6],w17=wl1[7];
            const double w20=wl2[0],w21=wl2[1],w22=wl2[2],w23=wl2[3],
                         w24=wl2[4],w25=wl2[5],w26=wl2[6],w27=wl2[7];
            const double w30=wl3[0],w31=wl3[1],w32=wl3[2],w33=wl3[3],
                         w34=wl3[4],w35=wl3[5],w36=wl3[6],w37=wl3[7];
            const double* xb = sb + kk;
            #pragma unroll
            for (int bi = 0; bi < 8; ++bi){
              const double* xp = xb + (((bgi<<3)+bi)<<5);
              ROWFMA(acc[bi*4+0],acc[bi*4+1],acc[bi*4+2],acc[bi*4+3], xp);
            }
          }
          __syncthreads();
        }

        // store partials: j = jt*256 + r*64 + jg (consecutive lanes -> consecutive j)
        float* pbase = (isA ? pAf : pDf) + ((size_t)ks*NB)*NGATE;
        #pragma unroll
        for (int bi = 0; bi < 8; ++bi){
          const int b = (bgi<<3) + bi;
          float* pp = pbase + (size_t)b*NGATE + jt*256 + jg;
          st_f(pp,       (float)acc[bi*4+0]);
          st_f(pp + 64,  (float)acc[bi*4+1]);
          st_f(pp + 128, (float)acc[bi*4+2]);
          st_f(pp + 192, (float)acc[bi*4+3]);
        }
      }
    }
    gridbar(flags, gen, wg, tid, ++g);

    // ---- PH1b: LSTM reduce + activations (+ pq), and prenet(t+1) on WGs 64..95 ----
    if (wg < NB){
      if (t < TOUT){
        const int b = wg;
        for (int h = tid; h < ARNN; h += TPB){
          double g0 = (double)P.bihA[h]      + (double)P.bhhA[h];
          double g1 = (double)P.bihA[1024+h] + (double)P.bhhA[1024+h];
          double g2 = (double)P.bihA[2048+h] + (double)P.bhhA[2048+h];
          double g3 = (double)P.bihA[3072+h] + (double)P.bhhA[3072+h];
          for (int p2 = 0; p2 < KSA; ++p2){
            const float* pp = pAf + ((size_t)p2*NB + b)*NGATE;
            g0 += (double)ld_f(pp + h);        g1 += (double)ld_f(pp + 1024 + h);
            g2 += (double)ld_f(pp + 2048 + h); g3 += (double)ld_f(pp + 3072 + h);
          }
          const double cp = ac[b*ARNN + h];
          const double cn = sigd(g1)*cp + sigd(g0)*tanh(g2);
          const double hn = sigd(g3)*tanh(cn);
          ac[b*ARNN+h] = cn;             // private: normal cached
          st_d(ah + b*ARNN + h, hn);     // shared: sc1
          sb[h] = hn;
        }
        __syncthreads();
        {
          const int a2 = tid >> 1, hf = tid & 1;
          const float* wq = P.Wq + (size_t)a2*ARNN + hf*512;
          const double* xh = sb + hf*512;
          double s = 0.0;
          for (int h2 = 0; h2 < 512; ++h2) s += (double)wq[h2]*xh[h2];
          sb[1024 + tid] = s;
        }
        __syncthreads();
        if (tid < ADIM) st_d(pq + b*ADIM + tid, sb[1024 + 2*tid] + sb[1024 + 2*tid + 1]);
      }
    } else if (wg < 2*NB){
      if (t > 0){
        const int b = wg - NB;
        for (int h = tid; h < ARNN; h += TPB){
          double g0 = (double)P.bihD[h]      + (double)P.bhhD[h];
          double g1 = (double)P.bihD[1024+h] + (double)P.bhhD[1024+h];
          double g2 = (double)P.bihD[2048+h] + (double)P.bhhD[2048+h];
          double g3 = (double)P.bihD[3072+h] + (double)P.bhhD[3072+h];
          for (int p2 = 0; p2 < KSD; ++p2){
            const float* pp = pDf + ((size_t)p2*NB + b)*NGATE;
            g0 += (double)ld_f(pp + h);        g1 += (double)ld_f(pp + 1024 + h);
            g2 += (double)ld_f(pp + 2048 + h); g3 += (double)ld_f(pp + 3072 + h);
          }
          const double cp = dc[b*ARNN + h];
          const double cn = sigd(g1)*cp + sigd(g0)*tanh(g2);
          const double hn = sigd(g3)*tanh(cn);
          dc[b*ARNN+h] = cn;             // private: normal
          st_d(dh + b*ARNN + h, hn);     // shared: sc1
        }
      }
    } else if (wg < 3*NB){
      if (t < TOUT-1){
        // prenet for step t+1 (depends only on dec input; PRE double-buffer by parity)
        const int b = wg - 2*NB, t1 = t + 1;
        double* pre_next = ws + ((t1 & 1) ? PRE1_OFF : PRE0_OFF);
        for (int m = tid; m < NMEL; m += TPB)
          sb[m] = (double)P.dec[((size_t)b*NMEL + m)*TOUT + (t1-1)];
        __syncthreads();
        uint32_t d1k0, d1k1, d2k0, d2k1;
        tf_block(0u, 42u, 0u, 0u, d1k0, d1k1);
        tf_block(0u, 42u, 0u, 1u, d2k0, d2k1);
        const uint32_t flat = ((uint32_t)(t1*NB + b))*PDIM + tid;
        {
          const float* w = P.Wpre1 + tid*NMEL;
          double s = 0.0;
          for (int m = 0; m < NMEL; ++m) s += sb[m]*(double)w[m];
          double hv = tf_keep_part(d1k0, d1k1, flat) ? s*2.0 : 0.0;
          sb[128 + tid] = fmax(hv, 0.0);
        }
        __syncthreads();
        {
          const float* w = P.Wpre2 + tid*PDIM;
          double s = 0.0;
          for (int m = 0; m < PDIM; ++m) s += sb[128+m]*(double)w[m];
          double pv = tf_keep_part(d2k0, d2k1, flat) ? s*2.0 : 0.0;
          st_d(pre_next + (b<<8) + tid, fmax(pv, 0.0));
        }
      }
    }
    gridbar(flags, gen, wg, tid, ++g);

    // ---- PH2: attention energies (t) + mel/gate (t-1), fp64 ----
    if (wg < 224){
      if (t < TOUT){
        const int b = wg / 7, tt = wg - b*7;
        const int tbase = tt*64;
        if (tid < ADIM) sb[tid] = ld_d(pq + b*ADIM + tid);
        for (int i = tid; i < 94; i += TPB){
          int tg = tbase - 15 + i;
          sb[128 + i] = (tg >= 0 && tg < TIN) ? ld_d(aw + b*TIN + tg) : 0.0;
        }
        for (int i = tid; i < 94; i += TPB){
          int tg = tbase - 15 + i;
          sb[222 + i] = (tg >= 0 && tg < TIN) ? ld_d(awc + b*TIN + tg) : 0.0;
        }
        __syncthreads();
        const int wv = tid >> 6, lane = tid & 63;
        const int tg = tbase + lane;
        double esum = 0.0;
        if (tg < TIN){
          double w0r[31], w1r[31];
          #pragma unroll
          for (int k = 0; k < 31; ++k){ w0r[k] = sb[128 + lane + k]; w1r[k] = sb[222 + lane + k]; }
          const double* pmrow = pmT + (size_t)b*ADIM*TIN + tg;
          for (int a2 = wv*32; a2 < wv*32 + 32; ++a2){
            const double* wf = wfc + a2*62;
            double cv = 0.0;
            #pragma unroll
            for (int k = 0; k < 31; ++k) cv += wf[k]*w0r[k];
            #pragma unroll
            for (int k = 0; k < 31; ++k) cv += wf[31+k]*w1r[k];
            const double e = sb[a2] + cv + pmrow[(size_t)a2*TIN];
            esum += (double)P.v[a2]*tanh(e);
          }
        }
        sb[640 + wv*64 + lane] = esum;
        __syncthreads();
        if (tid < 64){
          const int tg2 = tbase + tid;
          if (tg2 < TIN){
            double e = sb[640+tid] + sb[704+tid] + sb[768+tid] + sb[832+tid];
            if (P.mask[b*TIN + tg2]) e = -1e9;
            st_d(en + b*TIN + tg2, e);
          }
        }
      }
    } else if (wg < 256){
      if (t > 0){
        const int b = wg - 224, ts = t-1;
        for (int i = tid; i < 1536; i += TPB)
          sb[i] = (i < 1024) ? ld_d(dh + b*ARNN + i) : ld_d(ctx + b*EDIM + (i-1024));
        __syncthreads();
        const int o = tid >> 1, hf = tid & 1;
        double s = 0.0;
        if (o <= 80){
          const float* wr = ((o < 80) ? (P.Wp + (size_t)o*1536) : P.Wg) + hf*768;
          const double* xr = sb + hf*768;
          for (int m2 = 0; m2 < 768; ++m2) s += (double)wr[m2]*xr[m2];
        }
        sb[1600 + tid] = s;
        __syncthreads();
        if (tid <= 80){
          double val = sb[1600 + 2*tid] + sb[1600 + 2*tid + 1];
          if (tid < 80) P.out[MEL_OFF + ((size_t)b*NMEL + tid)*TOUT + ts] = (float)(val + (double)P.bp[tid]);
          else          P.out[GATE_OFF + (size_t)b*TOUT + ts] = (float)(val + (double)P.bg[0]);
        }
      }
    }
    gridbar(flags, gen, wg, tid, ++g);

    // ---- PH3: softmax (redundant x8) + ctx slice on ALL 256 WGs ----
    if (t < TOUT){
      const int b = wg >> 3, s = wg & 7;
      double m = -1.0e300;
      for (int i = tid; i < TIN; i += TPB){
        double e = ld_d(en + b*TIN + i);
        sb[512 + i] = e;
        m = fmax(m, e);
      }
      sb[tid] = m; __syncthreads();
      for (int s2 = TPB/2; s2 > 0; s2 >>= 1){
        if (tid < s2) sb[tid] = fmax(sb[tid], sb[tid+s2]);
        __syncthreads();
      }
      const double mx = sb[0];
      __syncthreads();
      double ssum = 0.0;
      for (int i = tid; i < TIN; i += TPB){
        double u = exp(sb[512+i] - mx);
        sb[512 + i] = u; ssum += u;
      }
      sb[tid] = ssum; __syncthreads();
      for (int s2 = TPB/2; s2 > 0; s2 >>= 1){
        if (tid < s2) sb[tid] += sb[tid+s2];
        __syncthreads();
      }
      const double tot = sb[0];
      __syncthreads();
      for (int i = tid; i < TIN; i += TPB){
        double a2 = sb[512+i] / tot;
        sb[512+i] = a2;
        if (s == 0){
          st_d(aw + b*TIN + i, a2);
          st_d(awc + b*TIN + i, ld_d(awc + b*TIN + i) + a2);
          P.out[AL_OFF + ((size_t)b*TOUT + t)*TIN + i] = (float)a2;
        }
      }
      __syncthreads();
      {
        const int e2 = s*64 + (tid & 63);
        const int tc = tid >> 6;                     // 0..3 -> t-chunks of 100
        const float* mcol = P.memory + (size_t)b*TIN*EDIM + e2;
        double sacc = 0.0;
        for (int t2 = tc*100; t2 < tc*100 + 100; ++t2)
          sacc += sb[512+t2] * (double)mcol[(size_t)t2*EDIM];
        sb[1024 + tid] = sacc;
        __syncthreads();
        if (tid < 64){
          double v4 = sb[1024+tid] + sb[1088+tid] + sb[1152+tid] + sb[1216+tid];
          st_d(ctx + b*EDIM + s*64 + tid, v4);
        }
      }
    }
    gridbar(flags, gen, wg, tid, ++g);
  }
}

extern "C" void kernel_launch(void* const* d_in, const int* in_sizes, int n_in,
                              void* d_out, int out_size, void* d_ws, size_t ws_size,
                              hipStream_t stream)
{
  const float* memory = (const float*)d_in[0];
  const float* dec    = (const float*)d_in[1];
  const unsigned char* mask = (const unsigned char*)d_in[2];
  const float* W_pre1 = (const float*)d_in[3];
  const float* W_pre2 = (const float*)d_in[4];
  const float* WihA   = (const float*)d_in[5];
  const float* WhhA   = (const float*)d_in[6];
  const float* bihA   = (const float*)d_in[7];
  const float* bhhA   = (const float*)d_in[8];
  const float* Wq     = (const float*)d_in[9];
  const float* Wm     = (const float*)d_in[10];
  const float* v      = (const float*)d_in[11];
  const float* Wc     = (const float*)d_in[12];
  const float* Wd     = (const float*)d_in[13];
  const float* WihD   = (const float*)d_in[14];
  const float* WhhD   = (const float*)d_in[15];
  const float* bihD   = (const float*)d_in[16];
  const float* bhhD   = (const float*)d_in[17];
  const float* Wp     = (const float*)d_in[18];
  const float* bp     = (const float*)d_in[19];
  const float* Wg     = (const float*)d_in[20];
  const float* bg     = (const float*)d_in[21];

  double* ws = (double*)d_ws;
  float* out = (float*)d_out;

  if (ws_size < WS_BYTES){
    sentinel_kernel<<<1, 1, 0, stream>>>(out, 12345.0f);   // diagnostic: ws too small
    return;
  }

  unsigned* bar = (unsigned*)((float*)(ws + DBL_END) + F_END);
  bar_init_kernel<<<1, TPB, 0, stream>>>(bar);
  pm_kernel<<<NB*TIN, TPB, 0, stream>>>(memory, Wm, ws + PM_OFF);
  wfc_kernel<<<1, TPB, 0, stream>>>(Wd, Wc, ws + WFC_OFF);

  DecParams P;
  P.memory = memory; P.dec = dec;
  P.Wpre1 = W_pre1; P.Wpre2 = W_pre2;
  P.WihA = WihA; P.WhhA = WhhA; P.bihA = bihA; P.bhhA = bhhA;
  P.Wq = Wq; P.v = v;
  P.WihD = WihD; P.WhhD = WhhD; P.bihD = bihD; P.bhhD = bhhD;
  P.Wp = Wp; P.bp = bp; P.Wg = Wg; P.bg = bg;
  P.mask = mask; P.ws = ws; P.out = out;

  decoder_main<<<GRID_WGS, TPB, 0, stream>>>(P);
}

// Round 7
// 95091.357 us; speedup vs baseline: 1.2170x; 1.2170x over previous
//
#include <hip/hip_runtime.h>
#include <cstdint>

#define TPB 256
#define GRID_WGS 256

// problem dims
#define NB    32
#define TIN   400
#define TOUT  500
#define NMEL  80
#define EDIM  512
#define ARNN  1024
#define PDIM  256
#define ADIM  128
#define NGATE 4096

#define KSA 7        // attention-LSTM K = 1792 = 7 x 256
#define KSD 8        // decoder-LSTM   K = 2560 = 8 x 320
// K1 task split: A = 16 jt x 7 ks x 2 bhalf = 224; D = 16 x 8 x 2 = 256; total 480
#define K1_GRID 480

// double-region offsets (units: doubles)
#define PM_OFF   0          // pmT[b][a][t] [32][128][400]
#define WFC_OFF  1638400    // [128][62]
#define AH_OFF   1646336
#define AC_OFF   1679104
#define DH_OFF   1711872
#define DC_OFF   1744640
#define CTX_OFF  1777408
#define AW_OFF   1793792
#define AWC_OFF  1806592
#define EN_OFF   1819392
#define PQ_OFF   1832192
#define PRE0_OFF 1836288
#define PRE1_OFF 1844480
#define DBL_END  1852672
// float region (units: floats, base = (float*)(ws + DBL_END))
#define PAF_OFF  0          // A partials [7][32][4096]
#define PDF_OFF  917504     // D partials [8][32][4096]
#define F_END    1966080
// (legacy barrier region kept in WS_BYTES so the workspace guard is unchanged)
#define BAR_UINTS 320
#define WS_BYTES ((size_t)DBL_END*8 + (size_t)F_END*4 + (size_t)BAR_UINTS*4)

#define MEL_OFF  0
#define GATE_OFF 1280000
#define AL_OFF   1296000

// ---------------- threefry2x32 core (bit-exact JAX) ----------------
__device__ __forceinline__ uint32_t rotl32(uint32_t v, int r){ return (v<<r)|(v>>(32-r)); }

__device__ __forceinline__ void tf_block(uint32_t k0, uint32_t k1, uint32_t x0, uint32_t x1,
                                         uint32_t& y0, uint32_t& y1){
  uint32_t k2 = k0 ^ k1 ^ 0x1BD11BDAu;
  x0 += k0; x1 += k1;
#define TF4(r0,r1,r2,r3,ka,kb,inc) \
  x0 += x1; x1 = rotl32(x1,r0); x1 ^= x0; \
  x0 += x1; x1 = rotl32(x1,r1); x1 ^= x0; \
  x0 += x1; x1 = rotl32(x1,r2); x1 ^= x0; \
  x0 += x1; x1 = rotl32(x1,r3); x1 ^= x0; \
  x0 += (ka); x1 += (kb) + (inc);
  TF4(13,15,26,6,  k1,k2,1u)
  TF4(17,29,16,24, k2,k0,2u)
  TF4(13,15,26,6,  k0,k1,3u)
  TF4(17,29,16,24, k1,k2,4u)
  TF4(13,15,26,6,  k2,k0,5u)
#undef TF4
  y0 = x0; y1 = x1;
}

__device__ __forceinline__ bool tf_keep_part(uint32_t k0, uint32_t k1, uint32_t i){
  uint32_t y0, y1;
  tf_block(k0, k1, 0u, i, y0, y1);
  return (((y0 ^ y1) >> 31) == 0u);
}

// ---------------- precompute kernels (fp64) ----------------
__global__ __launch_bounds__(TPB) void pm_kernel(
    const float* __restrict__ memory, const float* __restrict__ Wm, double* __restrict__ pmT)
{
  const int bt = blockIdx.x;           // b*400 + t
  const int b = bt / TIN, t2 = bt - b*TIN;
  const int tid = threadIdx.x;
  __shared__ double sm[EDIM];
  __shared__ double sp[TPB];
  for (int i = tid; i < EDIM; i += TPB) sm[i] = (double)memory[(size_t)bt*EDIM + i];
  __syncthreads();
  const int a = tid & 127, hf = tid >> 7;
  const float* w = Wm + (size_t)a*EDIM + hf*256;
  const double* x = sm + hf*256;
  double s = 0.0;
  for (int e = 0; e < 256; ++e) s += (double)w[e]*x[e];
  sp[tid] = s;
  __syncthreads();
  if (tid < ADIM) pmT[((size_t)b*ADIM + tid)*TIN + t2] = sp[tid] + sp[tid+128];
}

__global__ __launch_bounds__(TPB) void wfc_kernel(
    const float* __restrict__ Wd, const float* __restrict__ Wc, double* __restrict__ wfc)
{
  for (int o = threadIdx.x; o < ADIM*62; o += TPB){
    int a = o / 62, ck = o - a*62;
    double s = 0.0;
    for (int f = 0; f < 32; ++f) s += (double)Wd[a*32+f]*(double)Wc[f*62 + ck];
    wfc[o] = s;
  }
}

__global__ __launch_bounds__(TPB) void zero_kernel(double* ws){
  for (size_t i = (size_t)blockIdx.x*TPB + threadIdx.x; i < (size_t)(DBL_END - AH_OFF);
       i += (size_t)GRID_WGS*TPB)
    ws[AH_OFF + i] = 0.0;
}

__global__ void sentinel_kernel(float* out, float val){ out[0] = val; }

// ---------------- params ----------------
struct DecParams {
  const float *memory, *dec;
  const float *Wpre1, *Wpre2;
  const float *WihA,*WhhA,*bihA,*bhhA;
  const float *Wq,*v;
  const float *WihD,*WhhD,*bihD,*bhhD;
  const float *Wp,*bp,*Wg,*bg;
  const unsigned char* mask;
  double* ws;
  float* out;
};

__device__ __forceinline__ double sigd(double x){ return 1.0/(1.0+exp(-x)); }

// 4 outputs x 8 k fp64 FMA block (w?? scalars must be in scope)
#define ROWFMA(a0,a1,a2,a3, xp) do{ \
  const double x0=(xp)[0],x1=(xp)[1],x2=(xp)[2],x3=(xp)[3], \
               x4=(xp)[4],x5=(xp)[5],x6=(xp)[6],x7=(xp)[7]; \
  a0 += w00*x0+w01*x1+w02*x2+w03*x3+w04*x4+w05*x5+w06*x6+w07*x7; \
  a1 += w10*x0+w11*x1+w12*x2+w13*x3+w14*x4+w15*x5+w16*x6+w17*x7; \
  a2 += w20*x0+w21*x1+w22*x2+w23*x3+w24*x4+w25*x5+w26*x6+w27*x7; \
  a3 += w30*x0+w31*x1+w32*x2+w33*x3+w34*x4+w35*x5+w36*x6+w37*x7; \
}while(0)

// ---------------- K1: gate-GEMM partials (A for t, D for t-1) --------------------------
// 480 blocks (~2/CU): task = (isA, jt, ks, bhalf); each task does 256 j x 16 b x kspan.
__global__ __launch_bounds__(TPB, 2) void k1_gemm(DecParams P, int t)
{
  const int task = blockIdx.x, tid = threadIdx.x;
  const bool isA = task < 224;
  if (isA ? (t >= TOUT) : (t == 0)) return;
  __shared__ __align__(16) double sb[2048];   // X tile: 16 b x 128 k

  double* ws = P.ws;
  const double* pre_cur = ws + ((t & 1) ? PRE1_OFF : PRE0_OFF);
  const double* ctx = ws + CTX_OFF;
  const double* ah  = ws + AH_OFF;
  const double* dh  = ws + DH_OFF;
  float* pAf = (float*)(ws + DBL_END);
  float* pDf = pAf + PDF_OFF;

  int jt, ks, bh, kbase;
  if (isA){ const int q = task;     jt = q/14; const int r = q - jt*14; ks = r>>1; bh = r&1; kbase = ks*256; }
  else    { const int q = task-224; jt = q/16; const int r = q - jt*16; ks = r>>1; bh = r&1; kbase = ks*320; }
  const int b0 = bh*16;
  const int jg = tid & 63, bgi = tid >> 6;
  const int j0 = jt*256 + jg*4;
  double acc[16];
  #pragma unroll
  for (int i = 0; i < 16; ++i) acc[i] = 0.0;

  const int npieces = isA ? 2 : 3;
  #pragma unroll 1
  for (int pc = 0; pc < npieces; ++pc){
    const int poff = pc*128;
    const int len  = (isA || pc < 2) ? 128 : 64;
    const int kb2  = kbase + poff;
    // stage X[16 b][len k] into sb[bl*128 + kloc]
    if (len == 128){
      for (int i = tid; i < 16*128; i += TPB){
        const int bl = i >> 7, kloc = i & 127, kg = kb2 + kloc, b = b0 + bl;
        double xv;
        if (isA){
          if (kg < 256)       xv = pre_cur[(b<<8) + kg];
          else if (kg < 768)  xv = ctx[b*EDIM + (kg-256)];
          else                xv = ah[b*ARNN + (kg-768)];
        } else {
          if (kg < 1024)      xv = ah[b*ARNN + kg];
          else if (kg < 1536) xv = ctx[b*EDIM + (kg-1024)];
          else                xv = dh[b*ARNN + (kg-1536)];
        }
        sb[(bl<<7) + kloc] = xv;
      }
    } else {
      for (int i = tid; i < 16*64; i += TPB){
        const int bl = i >> 6, kloc = i & 63, kg = kb2 + kloc, b = b0 + bl;
        double xv;
        if (kg < 1024)      xv = ah[b*ARNN + kg];
        else if (kg < 1536) xv = ctx[b*EDIM + (kg-1024)];
        else                xv = dh[b*ARNN + (kg-1536)];
        sb[(bl<<6) + kloc + ((bl<<6))] = 0.0;  // placeholder overwritten below
        sb[(bl<<7) + kloc] = xv;
      }
    }
    __syncthreads();
    // weight rows for this piece (pieces never straddle the ih/hh boundary)
    const float* wbase; int rowlen, koff;
    if (isA){
      if (kb2 < 768){ wbase = P.WihA; rowlen = 768;  koff = kb2; }
      else          { wbase = P.WhhA; rowlen = 1024; koff = kb2-768; }
    } else {
      if (kb2 < 1536){ wbase = P.WihD; rowlen = 1536; koff = kb2; }
      else           { wbase = P.WhhD; rowlen = 1024; koff = kb2-1536; }
    }
    const float* w0p = wbase + (size_t)(j0+0)*rowlen + koff;
    const float* w1p = wbase + (size_t)(j0+1)*rowlen + koff;
    const float* w2p = wbase + (size_t)(j0+2)*rowlen + koff;
    const float* w3p = wbase + (size_t)(j0+3)*rowlen + koff;
    // 1-deep register prefetch: load k-block kk+8 while computing kk (R5-proven)
    float4 c00=*(const float4*)(w0p),   c01=*(const float4*)(w0p+4);
    float4 c10=*(const float4*)(w1p),   c11=*(const float4*)(w1p+4);
    float4 c20=*(const float4*)(w2p),   c21=*(const float4*)(w2p+4);
    float4 c30=*(const float4*)(w3p),   c31=*(const float4*)(w3p+4);
    #pragma unroll 1
    for (int kk = 0; kk < len; kk += 8){
      const int kn = (kk + 8 < len) ? (kk + 8) : kk;   // clamp: last iter reloads
      float4 n00=*(const float4*)(w0p+kn), n01=*(const float4*)(w0p+kn+4);
      float4 n10=*(const float4*)(w1p+kn), n11=*(const float4*)(w1p+kn+4);
      float4 n20=*(const float4*)(w2p+kn), n21=*(const float4*)(w2p+kn+4);
      float4 n30=*(const float4*)(w3p+kn), n31=*(const float4*)(w3p+kn+4);
      {
        const double w00=c00.x,w01=c00.y,w02=c00.z,w03=c00.w,
                     w04=c01.x,w05=c01.y,w06=c01.z,w07=c01.w;
        const double w10=c10.x,w11=c10.y,w12=c10.z,w13=c10.w,
                     w14=c11.x,w15=c11.y,w16=c11.z,w17=c11.w;
        const double w20=c20.x,w21=c20.y,w22=c20.z,w23=c20.w,
                     w24=c21.x,w25=c21.y,w26=c21.z,w27=c21.w;
        const double w30=c30.x,w31=c30.y,w32=c30.z,w33=c30.w,
                     w34=c31.x,w35=c31.y,w36=c31.z,w37=c31.w;
        const double* xb = sb + kk;
        #pragma unroll
        for (int bi = 0; bi < 4; ++bi){
          const double* xp = xb + (((bgi<<2)+bi)<<7);
          ROWFMA(acc[bi*4+0],acc[bi*4+1],acc[bi*4+2],acc[bi*4+3], xp);
        }
      }
      c00=n00;c01=n01;c10=n10;c11=n11;c20=n20;c21=n21;c30=n30;c31=n31;
    }
    __syncthreads();
  }

  float* pbase = (isA ? pAf : pDf) + ((size_t)ks*NB)*NGATE;
  #pragma unroll
  for (int bi = 0; bi < 4; ++bi){
    const int b = b0 + (bgi<<2) + bi;
    float4 v4 = { (float)acc[bi*4+0], (float)acc[bi*4+1],
                  (float)acc[bi*4+2], (float)acc[bi*4+3] };
    *(float4*)(pbase + (size_t)b*NGATE + j0) = v4;
  }
}

// ---------------- K2: LSTM reduce + activations (+ pq) + prenet(t+1) ------------------
__global__ __launch_bounds__(TPB) void k2_reduce(DecParams P, int t)
{
  const int wg = blockIdx.x, tid = threadIdx.x;
  __shared__ double sb[1536];
  double* ws = P.ws;
  double* ah  = ws + AH_OFF;   double* ac  = ws + AC_OFF;
  double* dh  = ws + DH_OFF;   double* dc  = ws + DC_OFF;
  double* pq  = ws + PQ_OFF;
  float*  pAf = (float*)(ws + DBL_END);
  float*  pDf = pAf + PDF_OFF;

  if (wg < NB){
    if (t < TOUT){
      const int b = wg;
      for (int h = tid; h < ARNN; h += TPB){
        double g0 = (double)P.bihA[h]      + (double)P.bhhA[h];
        double g1 = (double)P.bihA[1024+h] + (double)P.bhhA[1024+h];
        double g2 = (double)P.bihA[2048+h] + (double)P.bhhA[2048+h];
        double g3 = (double)P.bihA[3072+h] + (double)P.bhhA[3072+h];
        for (int p2 = 0; p2 < KSA; ++p2){
          const float* pp = pAf + ((size_t)p2*NB + b)*NGATE;
          g0 += (double)pp[h];        g1 += (double)pp[1024+h];
          g2 += (double)pp[2048+h];   g3 += (double)pp[3072+h];
        }
        const double cp = ac[b*ARNN + h];
        const double cn = sigd(g1)*cp + sigd(g0)*tanh(g2);
        const double hn = sigd(g3)*tanh(cn);
        ac[b*ARNN+h] = cn; ah[b*ARNN+h] = hn; sb[h] = hn;
      }
      __syncthreads();
      {
        const int a2 = tid >> 1, hf = tid & 1;
        const float* wq = P.Wq + (size_t)a2*ARNN + hf*512;
        const double* xh = sb + hf*512;
        double s = 0.0;
        for (int h2 = 0; h2 < 512; ++h2) s += (double)wq[h2]*xh[h2];
        sb[1024 + tid] = s;
      }
      __syncthreads();
      if (tid < ADIM) pq[b*ADIM + tid] = sb[1024 + 2*tid] + sb[1024 + 2*tid + 1];
    }
  } else if (wg < 2*NB){
    if (t > 0){
      const int b = wg - NB;
      for (int h = tid; h < ARNN; h += TPB){
        double g0 = (double)P.bihD[h]      + (double)P.bhhD[h];
        double g1 = (double)P.bihD[1024+h] + (double)P.bhhD[1024+h];
        double g2 = (double)P.bihD[2048+h] + (double)P.bhhD[2048+h];
        double g3 = (double)P.bihD[3072+h] + (double)P.bhhD[3072+h];
        for (int p2 = 0; p2 < KSD; ++p2){
          const float* pp = pDf + ((size_t)p2*NB + b)*NGATE;
          g0 += (double)pp[h];        g1 += (double)pp[1024+h];
          g2 += (double)pp[2048+h];   g3 += (double)pp[3072+h];
        }
        const double cp = dc[b*ARNN + h];
        const double cn = sigd(g1)*cp + sigd(g0)*tanh(g2);
        const double hn = sigd(g3)*tanh(cn);
        dc[b*ARNN+h] = cn; dh[b*ARNN+h] = hn;
      }
    }
  } else {
    if (t < TOUT-1){
      const int b = wg - 2*NB, t1 = t + 1;
      double* pre_next = ws + ((t1 & 1) ? PRE1_OFF : PRE0_OFF);
      for (int m = tid; m < NMEL; m += TPB)
        sb[m] = (double)P.dec[((size_t)b*NMEL + m)*TOUT + (t1-1)];
      __syncthreads();
      uint32_t d1k0, d1k1, d2k0, d2k1;
      tf_block(0u, 42u, 0u, 0u, d1k0, d1k1);
      tf_block(0u, 42u, 0u, 1u, d2k0, d2k1);
      const uint32_t flat = ((uint32_t)(t1*NB + b))*PDIM + tid;
      {
        const float* w = P.Wpre1 + tid*NMEL;
        double s = 0.0;
        for (int m = 0; m < NMEL; ++m) s += sb[m]*(double)w[m];
        double hv = tf_keep_part(d1k0, d1k1, flat) ? s*2.0 : 0.0;
        sb[128 + tid] = fmax(hv, 0.0);
      }
      __syncthreads();
      {
        const float* w = P.Wpre2 + tid*PDIM;
        double s = 0.0;
        for (int m = 0; m < PDIM; ++m) s += sb[128+m]*(double)w[m];
        double pv = tf_keep_part(d2k0, d2k1, flat) ? s*2.0 : 0.0;
        pre_next[(b<<8) + tid] = fmax(pv, 0.0);
      }
    }
  }
}

// ---------------- K3: attention energies (t) + mel/gate (t-1) -------------------------
__global__ __launch_bounds__(TPB) void k3_att(DecParams P, int t)
{
  const int wg = blockIdx.x, tid = threadIdx.x;
  __shared__ double sb[1856];
  double* ws = P.ws;
  double* pmT = ws + PM_OFF;   double* wfc = ws + WFC_OFF;
  double* dh  = ws + DH_OFF;   double* ctx = ws + CTX_OFF;
  double* aw  = ws + AW_OFF;   double* awc = ws + AWC_OFF;
  double* en  = ws + EN_OFF;   double* pq  = ws + PQ_OFF;

  if (wg < 224){
    if (t < TOUT){
      const int b = wg / 7, tt = wg - b*7;
      const int tbase = tt*64;
      if (tid < ADIM) sb[tid] = pq[b*ADIM + tid];
      for (int i = tid; i < 94; i += TPB){
        int tg = tbase - 15 + i;
        sb[128 + i] = (tg >= 0 && tg < TIN) ? aw[b*TIN + tg] : 0.0;
      }
      for (int i = tid; i < 94; i += TPB){
        int tg = tbase - 15 + i;
        sb[222 + i] = (tg >= 0 && tg < TIN) ? awc[b*TIN + tg] : 0.0;
      }
      __syncthreads();
      const int wv = tid >> 6, lane = tid & 63;
      const int tg = tbase + lane;
      double esum = 0.0;
      if (tg < TIN){
        double w0r[31], w1r[31];
        #pragma unroll
        for (int k = 0; k < 31; ++k){ w0r[k] = sb[128 + lane + k]; w1r[k] = sb[222 + lane + k]; }
        const double* pmrow = pmT + (size_t)b*ADIM*TIN + tg;
        for (int a2 = wv*32; a2 < wv*32 + 32; ++a2){
          const double* wf = wfc + a2*62;
          double cv = 0.0;
          #pragma unroll
          for (int k = 0; k < 31; ++k) cv += wf[k]*w0r[k];
          #pragma unroll
          for (int k = 0; k < 31; ++k) cv += wf[31+k]*w1r[k];
          const double e = sb[a2] + cv + pmrow[(size_t)a2*TIN];
          esum += (double)P.v[a2]*tanh(e);
        }
      }
      sb[640 + wv*64 + lane] = esum;
      __syncthreads();
      if (tid < 64){
        const int tg2 = tbase + tid;
        if (tg2 < TIN){
          double e = sb[640+tid] + sb[704+tid] + sb[768+tid] + sb[832+tid];
          if (P.mask[b*TIN + tg2]) e = -1e9;
          en[b*TIN + tg2] = e;
        }
      }
    }
  } else {
    if (t > 0){
      const int b = wg - 224, ts = t-1;
      for (int i = tid; i < 1536; i += TPB)
        sb[i] = (i < 1024) ? dh[b*ARNN + i] : ctx[b*EDIM + (i-1024)];
      __syncthreads();
      const int o = tid >> 1, hf = tid & 1;
      double s = 0.0;
      if (o <= 80){
        const float* wr = ((o < 80) ? (P.Wp + (size_t)o*1536) : P.Wg) + hf*768;
        const double* xr = sb + hf*768;
        for (int m2 = 0; m2 < 768; ++m2) s += (double)wr[m2]*xr[m2];
      }
      sb[1600 + tid] = s;
      __syncthreads();
      if (tid <= 80){
        double val = sb[1600 + 2*tid] + sb[1600 + 2*tid + 1];
        if (tid < 80) P.out[MEL_OFF + ((size_t)b*NMEL + tid)*TOUT + ts] = (float)(val + (double)P.bp[tid]);
        else          P.out[GATE_OFF + (size_t)b*TOUT + ts] = (float)(val + (double)P.bg[0]);
      }
    }
  }
}

// ---------------- K4: softmax (redundant x8) + ctx slice on 256 blocks ----------------
__global__ __launch_bounds__(TPB) void k4_ctx(DecParams P, int t)
{
  if (t >= TOUT) return;
  const int wg = blockIdx.x, tid = threadIdx.x;
  __shared__ double sb[1280];
  double* ws = P.ws;
  double* ctx = ws + CTX_OFF;  double* aw  = ws + AW_OFF;  double* awc = ws + AWC_OFF;
  double* en  = ws + EN_OFF;

  const int b = wg >> 3, s = wg & 7;
  double m = -1.0e300;
  for (int i = tid; i < TIN; i += TPB){
    double e = en[b*TIN + i];
    sb[512 + i] = e;
    m = fmax(m, e);
  }
  sb[tid] = m; __syncthreads();
  for (int s2 = TPB/2; s2 > 0; s2 >>= 1){
    if (tid < s2) sb[tid] = fmax(sb[tid], sb[tid+s2]);
    __syncthreads();
  }
  const double mx = sb[0];
  __syncthreads();
  double ssum = 0.0;
  for (int i = tid; i < TIN; i += TPB){
    double u = exp(sb[512+i] - mx);
    sb[512 + i] = u; ssum += u;
  }
  sb[tid] = ssum; __syncthreads();
  for (int s2 = TPB/2; s2 > 0; s2 >>= 1){
    if (tid < s2) sb[tid] += sb[tid+s2];
    __syncthreads();
  }
  const double tot = sb[0];
  __syncthreads();
  for (int i = tid; i < TIN; i += TPB){
    double a2 = sb[512+i] / tot;
    sb[512+i] = a2;
    if (s == 0){
      aw[b*TIN+i] = a2;
      awc[b*TIN+i] += a2;
      P.out[AL_OFF + ((size_t)b*TOUT + t)*TIN + i] = (float)a2;
    }
  }
  __syncthreads();
  {
    const int e2 = s*64 + (tid & 63);
    const int tc = tid >> 6;                     // 0..3 -> t-chunks of 100
    const float* mcol = P.memory + (size_t)b*TIN*EDIM + e2;
    double sacc = 0.0;
    for (int t2 = tc*100; t2 < tc*100 + 100; ++t2)
      sacc += sb[512+t2] * (double)mcol[(size_t)t2*EDIM];
    sb[1024 + tid] = sacc;
    __syncthreads();
    if (tid < 64){
      double v4 = sb[1024+tid] + sb[1088+tid] + sb[1152+tid] + sb[1216+tid];
      ctx[b*EDIM + s*64 + tid] = v4;
    }
  }
}

extern "C" void kernel_launch(void* const* d_in, const int* in_sizes, int n_in,
                              void* d_out, int out_size, void* d_ws, size_t ws_size,
                              hipStream_t stream)
{
  const float* memory = (const float*)d_in[0];
  const float* dec    = (const float*)d_in[1];
  const unsigned char* mask = (const unsigned char*)d_in[2];
  const float* W_pre1 = (const float*)d_in[3];
  const float* W_pre2 = (const float*)d_in[4];
  const float* WihA   = (const float*)d_in[5];
  const float* WhhA   = (const float*)d_in[6];
  const float* bihA   = (const float*)d_in[7];
  const float* bhhA   = (const float*)d_in[8];
  const float* Wq     = (const float*)d_in[9];
  const float* Wm     = (const float*)d_in[10];
  const float* v      = (const float*)d_in[11];
  const float* Wc     = (const float*)d_in[12];
  const float* Wd     = (const float*)d_in[13];
  const float* WihD   = (const float*)d_in[14];
  const float* WhhD   = (const float*)d_in[15];
  const float* bihD   = (const float*)d_in[16];
  const float* bhhD   = (const float*)d_in[17];
  const float* Wp     = (const float*)d_in[18];
  const float* bp     = (const float*)d_in[19];
  const float* Wg     = (const float*)d_in[20];
  const float* bg     = (const float*)d_in[21];

  double* ws = (double*)d_ws;
  float* out = (float*)d_out;

  if (ws_size < WS_BYTES){
    sentinel_kernel<<<1, 1, 0, stream>>>(out, 12345.0f);   // diagnostic: ws too small
    return;
  }

  zero_kernel<<<GRID_WGS, TPB, 0, stream>>>(ws);
  pm_kernel<<<NB*TIN, TPB, 0, stream>>>(memory, Wm, ws + PM_OFF);
  wfc_kernel<<<1, TPB, 0, stream>>>(Wd, Wc, ws + WFC_OFF);

  DecParams P;
  P.memory = memory; P.dec = dec;
  P.Wpre1 = W_pre1; P.Wpre2 = W_pre2;
  P.WihA = WihA; P.WhhA = WhhA; P.bihA = bihA; P.bhhA = bhhA;
  P.Wq = Wq; P.v = v;
  P.WihD = WihD; P.WhhD = WhhD; P.bihD = bihD; P.bhhD = bhhD;
  P.Wp = Wp; P.bp = bp; P.Wg = Wg; P.bg = bg;
  P.mask = mask; P.ws = ws; P.out = out;

  for (int t = 0; t <= TOUT; ++t){
    k1_gemm<<<K1_GRID, TPB, 0, stream>>>(P, t);
    k2_reduce<<<3*NB, TPB, 0, stream>>>(P, t);
    k3_att<<<256, TPB, 0, stream>>>(P, t);
    if (t < TOUT) k4_ctx<<<256, TPB, 0, stream>>>(P, t);
  }
}

// Round 8
// 71497.498 us; speedup vs baseline: 1.6186x; 1.3300x over previous
//
#include <hip/hip_runtime.h>
#include <cstdint>

#define TPB 256
#define GRID_WGS 256

// problem dims
#define NB    32
#define TIN   400
#define TOUT  500
#define NMEL  80
#define EDIM  512
#define ARNN  1024
#define PDIM  256
#define ADIM  128
#define NGATE 4096

#define KSA 7        // attention-LSTM K = 1792 = 7 x 256
#define KSD 8        // decoder-LSTM   K = 2560 = 8 x 320
// K1 task split (NO weight duplication): A = 32 jt(128 rows) x 7 ks = 224;
// D = 32 x 8 = 256; total 480 blocks (~2/CU), each 128 j x 32 b x kspan.
#define K1_GRID 480

// double-region offsets (units: doubles)
#define PM_OFF   0          // pmT[b][a][t] [32][128][400]
#define WFC_OFF  1638400    // [128][62]
#define AH_OFF   1646336
#define AC_OFF   1679104
#define DH_OFF   1711872
#define DC_OFF   1744640
#define CTX_OFF  1777408
#define AW_OFF   1793792
#define AWC_OFF  1806592
#define EN_OFF   1819392
#define PQ_OFF   1832192
#define PRE0_OFF 1836288
#define PRE1_OFF 1844480
#define DBL_END  1852672
// float region (units: floats, base = (float*)(ws + DBL_END))
#define PAF_OFF  0          // A partials [7][32][4096]
#define PDF_OFF  917504     // D partials [8][32][4096]
#define WQT_OFF  1966080    // WqT[h][a]  [1024][128]
#define WPGT_OFF 2097152    // WpgT[m][o] [1536][81] (o=80 is gate row)
#define WPGT_LEN 124416
#define F_END    2221568
#define BAR_UINTS 320
#define WS_BYTES ((size_t)DBL_END*8 + (size_t)F_END*4 + (size_t)BAR_UINTS*4)

#define MEL_OFF  0
#define GATE_OFF 1280000
#define AL_OFF   1296000

// ---------------- threefry2x32 core (bit-exact JAX) ----------------
__device__ __forceinline__ uint32_t rotl32(uint32_t v, int r){ return (v<<r)|(v>>(32-r)); }

__device__ __forceinline__ void tf_block(uint32_t k0, uint32_t k1, uint32_t x0, uint32_t x1,
                                         uint32_t& y0, uint32_t& y1){
  uint32_t k2 = k0 ^ k1 ^ 0x1BD11BDAu;
  x0 += k0; x1 += k1;
#define TF4(r0,r1,r2,r3,ka,kb,inc) \
  x0 += x1; x1 = rotl32(x1,r0); x1 ^= x0; \
  x0 += x1; x1 = rotl32(x1,r1); x1 ^= x0; \
  x0 += x1; x1 = rotl32(x1,r2); x1 ^= x0; \
  x0 += x1; x1 = rotl32(x1,r3); x1 ^= x0; \
  x0 += (ka); x1 += (kb) + (inc);
  TF4(13,15,26,6,  k1,k2,1u)
  TF4(17,29,16,24, k2,k0,2u)
  TF4(13,15,26,6,  k0,k1,3u)
  TF4(17,29,16,24, k1,k2,4u)
  TF4(13,15,26,6,  k2,k0,5u)
#undef TF4
  y0 = x0; y1 = x1;
}

__device__ __forceinline__ bool tf_keep_part(uint32_t k0, uint32_t k1, uint32_t i){
  uint32_t y0, y1;
  tf_block(k0, k1, 0u, i, y0, y1);
  return (((y0 ^ y1) >> 31) == 0u);
}

// ---------------- precompute kernels ----------------
__global__ __launch_bounds__(TPB) void pm_kernel(
    const float* __restrict__ memory, const float* __restrict__ Wm, double* __restrict__ pmT)
{
  const int bt = blockIdx.x;           // b*400 + t
  const int b = bt / TIN, t2 = bt - b*TIN;
  const int tid = threadIdx.x;
  __shared__ double sm[EDIM];
  __shared__ double sp[TPB];
  for (int i = tid; i < EDIM; i += TPB) sm[i] = (double)memory[(size_t)bt*EDIM + i];
  __syncthreads();
  const int a = tid & 127, hf = tid >> 7;
  const float* w = Wm + (size_t)a*EDIM + hf*256;
  const double* x = sm + hf*256;
  double s = 0.0;
  for (int e = 0; e < 256; ++e) s += (double)w[e]*x[e];
  sp[tid] = s;
  __syncthreads();
  if (tid < ADIM) pmT[((size_t)b*ADIM + tid)*TIN + t2] = sp[tid] + sp[tid+128];
}

__global__ __launch_bounds__(TPB) void wfc_kernel(
    const float* __restrict__ Wd, const float* __restrict__ Wc, double* __restrict__ wfc)
{
  for (int o = threadIdx.x; o < ADIM*62; o += TPB){
    int a = o / 62, ck = o - a*62;
    double s = 0.0;
    for (int f = 0; f < 32; ++f) s += (double)Wd[a*32+f]*(double)Wc[f*62 + ck];
    wfc[o] = s;
  }
}

// WqT[h*128 + a] = Wq[a*1024 + h]
__global__ __launch_bounds__(TPB) void wqt_kernel(const float* __restrict__ Wq, float* __restrict__ WqT){
  const int a = blockIdx.x;            // 0..127
  for (int h = threadIdx.x; h < ARNN; h += TPB)
    WqT[(size_t)h*ADIM + a] = Wq[(size_t)a*ARNN + h];
}

// WpgT[m*81 + o] = (o<80) ? Wp[o*1536 + m] : Wg[m]
__global__ __launch_bounds__(TPB) void wpgt_kernel(const float* __restrict__ Wp,
                                                   const float* __restrict__ Wg,
                                                   float* __restrict__ WpgT){
  for (int i = blockIdx.x*TPB + threadIdx.x; i < WPGT_LEN; i += 64*TPB){
    const int m = i / 81, o = i - m*81;
    WpgT[i] = (o < 80) ? Wp[(size_t)o*1536 + m] : Wg[m];
  }
}

__global__ __launch_bounds__(TPB) void zero_kernel(double* ws){
  for (size_t i = (size_t)blockIdx.x*TPB + threadIdx.x; i < (size_t)(DBL_END - AH_OFF);
       i += (size_t)GRID_WGS*TPB)
    ws[AH_OFF + i] = 0.0;
}

__global__ void sentinel_kernel(float* out, float val){ out[0] = val; }

// ---------------- params ----------------
struct DecParams {
  const float *memory, *dec;
  const float *Wpre1, *Wpre2;
  const float *WihA,*WhhA,*bihA,*bhhA;
  const float *Wq,*v;
  const float *WihD,*WhhD,*bihD,*bhhD;
  const float *Wp,*bp,*Wg,*bg;
  const unsigned char* mask;
  double* ws;
  float* out;
};

__device__ __forceinline__ double sigd(double x){ return 1.0/(1.0+exp(-x)); }

// 2 outputs x 8 k fp64 FMA block (w0?,w1? scalars must be in scope)
#define ROW2FMA(a0,a1, xp) do{ \
  const double x0=(xp)[0],x1=(xp)[1],x2=(xp)[2],x3=(xp)[3], \
               x4=(xp)[4],x5=(xp)[5],x6=(xp)[6],x7=(xp)[7]; \
  a0 += w00*x0+w01*x1+w02*x2+w03*x3+w04*x4+w05*x5+w06*x6+w07*x7; \
  a1 += w10*x0+w11*x1+w12*x2+w13*x3+w14*x4+w15*x5+w16*x6+w17*x7; \
}while(0)

// ---------------- K1: gate-GEMM partials (A for t, D for t-1) --------------------------
// 480 blocks: task = (isA, jt 0..31, ks); each block: 128 j x 32 b x kspan; each weight
// byte read exactly once per step. Lane jg owns rows {2jg, 2jg+1}; bgi owns 8 b.
__global__ __launch_bounds__(TPB, 2) void k1_gemm(DecParams P, int t)
{
  const int task = blockIdx.x, tid = threadIdx.x;
  const bool isA = task < 224;
  if (isA ? (t >= TOUT) : (t == 0)) return;
  __shared__ __align__(16) double sb[4096];   // X tile: 32 b x 128 k

  double* ws = P.ws;
  const double* pre_cur = ws + ((t & 1) ? PRE1_OFF : PRE0_OFF);
  const double* ctx = ws + CTX_OFF;
  const double* ah  = ws + AH_OFF;
  const double* dh  = ws + DH_OFF;
  float* pAf = (float*)(ws + DBL_END);
  float* pDf = pAf + PDF_OFF;

  int jt, ks, kbase;
  if (isA){ jt = task / KSA; ks = task - jt*KSA; kbase = ks*256; }
  else    { const int q = task-224; jt = q >> 3; ks = q & 7; kbase = ks*320; }
  const int jg = tid & 63, bgi = tid >> 6;
  const int j0 = jt*128 + jg*2;
  double acc[16];
  #pragma unroll
  for (int i = 0; i < 16; ++i) acc[i] = 0.0;

  const int npieces = isA ? 2 : 3;
  #pragma unroll 1
  for (int pc = 0; pc < npieces; ++pc){
    const int poff = pc*128;
    const int len  = (isA || pc < 2) ? 128 : 64;
    const int kb2  = kbase + poff;
    // stage X[32 b][len k] into sb[b*128 + kloc]
    if (len == 128){
      for (int i = tid; i < NB*128; i += TPB){
        const int b = i >> 7, kloc = i & 127, kg = kb2 + kloc;
        double xv;
        if (isA){
          if (kg < 256)       xv = pre_cur[(b<<8) + kg];
          else if (kg < 768)  xv = ctx[b*EDIM + (kg-256)];
          else                xv = ah[b*ARNN + (kg-768)];
        } else {
          if (kg < 1024)      xv = ah[b*ARNN + kg];
          else if (kg < 1536) xv = ctx[b*EDIM + (kg-1024)];
          else                xv = dh[b*ARNN + (kg-1536)];
        }
        sb[(b<<7) + kloc] = xv;
      }
    } else {
      for (int i = tid; i < NB*64; i += TPB){
        const int b = i >> 6, kloc = i & 63, kg = kb2 + kloc;
        double xv;
        if (kg < 1024)      xv = ah[b*ARNN + kg];
        else if (kg < 1536) xv = ctx[b*EDIM + (kg-1024)];
        else                xv = dh[b*ARNN + (kg-1536)];
        sb[(b<<7) + kloc] = xv;
      }
    }
    __syncthreads();
    // weight rows for this piece (pieces never straddle the ih/hh boundary)
    const float* wbase; int rowlen, koff;
    if (isA){
      if (kb2 < 768){ wbase = P.WihA; rowlen = 768;  koff = kb2; }
      else          { wbase = P.WhhA; rowlen = 1024; koff = kb2-768; }
    } else {
      if (kb2 < 1536){ wbase = P.WihD; rowlen = 1536; koff = kb2; }
      else           { wbase = P.WhhD; rowlen = 1024; koff = kb2-1536; }
    }
    const float* w0p = wbase + (size_t)(j0+0)*rowlen + koff;
    const float* w1p = wbase + (size_t)(j0+1)*rowlen + koff;
    // 1-deep register prefetch: load k-block kk+8 while computing kk
    float4 c00=*(const float4*)(w0p),   c01=*(const float4*)(w0p+4);
    float4 c10=*(const float4*)(w1p),   c11=*(const float4*)(w1p+4);
    #pragma unroll 1
    for (int kk = 0; kk < len; kk += 8){
      const int kn = (kk + 8 < len) ? (kk + 8) : kk;   // clamp: last iter reloads
      float4 n00=*(const float4*)(w0p+kn), n01=*(const float4*)(w0p+kn+4);
      float4 n10=*(const float4*)(w1p+kn), n11=*(const float4*)(w1p+kn+4);
      {
        const double w00=c00.x,w01=c00.y,w02=c00.z,w03=c00.w,
                     w04=c01.x,w05=c01.y,w06=c01.z,w07=c01.w;
        const double w10=c10.x,w11=c10.y,w12=c10.z,w13=c10.w,
                     w14=c11.x,w15=c11.y,w16=c11.z,w17=c11.w;
        const double* xb = sb + kk;
        #pragma unroll
        for (int bi = 0; bi < 8; ++bi){
          const double* xp = xb + (((bgi<<3)+bi)<<7);
          ROW2FMA(acc[bi*2+0], acc[bi*2+1], xp);
        }
      }
      c00=n00;c01=n01;c10=n10;c11=n11;
    }
    __syncthreads();
  }

  // store partials: float2 at j0 (consecutive lanes -> contiguous 512B per wave)
  float* pbase = (isA ? pAf : pDf) + ((size_t)ks*NB)*NGATE;
  #pragma unroll
  for (int bi = 0; bi < 8; ++bi){
    const int b = (bgi<<3) + bi;
    float2 v2 = { (float)acc[bi*2+0], (float)acc[bi*2+1] };
    *(float2*)(pbase + (size_t)b*NGATE + j0) = v2;
  }
}

// ---------------- K2: LSTM reduce + activations (+ pq) + prenet(t+1) ------------------
__global__ __launch_bounds__(TPB) void k2_reduce(DecParams P, int t)
{
  const int wg = blockIdx.x, tid = threadIdx.x;
  __shared__ double sb[1536];
  double* ws = P.ws;
  double* ah  = ws + AH_OFF;   double* ac  = ws + AC_OFF;
  double* dh  = ws + DH_OFF;   double* dc  = ws + DC_OFF;
  double* pq  = ws + PQ_OFF;
  float*  pAf = (float*)(ws + DBL_END);
  float*  pDf = pAf + PDF_OFF;
  const float* WqT = pAf + WQT_OFF;

  if (wg < NB){
    if (t < TOUT){
      const int b = wg;
      for (int h = tid; h < ARNN; h += TPB){
        double g0 = (double)P.bihA[h]      + (double)P.bhhA[h];
        double g1 = (double)P.bihA[1024+h] + (double)P.bhhA[1024+h];
        double g2 = (double)P.bihA[2048+h] + (double)P.bhhA[2048+h];
        double g3 = (double)P.bihA[3072+h] + (double)P.bhhA[3072+h];
        for (int p2 = 0; p2 < KSA; ++p2){
          const float* pp = pAf + ((size_t)p2*NB + b)*NGATE;
          g0 += (double)pp[h];        g1 += (double)pp[1024+h];
          g2 += (double)pp[2048+h];   g3 += (double)pp[3072+h];
        }
        const double cp = ac[b*ARNN + h];
        const double cn = sigd(g1)*cp + sigd(g0)*tanh(g2);
        const double hn = sigd(g3)*tanh(cn);
        ac[b*ARNN+h] = cn; ah[b*ARNN+h] = hn; sb[h] = hn;
      }
      __syncthreads();
      {
        const int a2 = tid >> 1, hf = tid & 1;
        const float* wqt = WqT + (size_t)(hf*512)*ADIM + a2;
        const double* xh = sb + hf*512;
        double s = 0.0;
        for (int h2 = 0; h2 < 512; ++h2) s += (double)wqt[(size_t)h2*ADIM]*xh[h2];
        sb[1024 + tid] = s;
      }
      __syncthreads();
      if (tid < ADIM) pq[b*ADIM + tid] = sb[1024 + 2*tid] + sb[1024 + 2*tid + 1];
    }
  } else if (wg < 2*NB){
    if (t > 0){
      const int b = wg - NB;
      for (int h = tid; h < ARNN; h += TPB){
        double g0 = (double)P.bihD[h]      + (double)P.bhhD[h];
        double g1 = (double)P.bihD[1024+h] + (double)P.bhhD[1024+h];
        double g2 = (double)P.bihD[2048+h] + (double)P.bhhD[2048+h];
        double g3 = (double)P.bihD[3072+h] + (double)P.bhhD[3072+h];
        for (int p2 = 0; p2 < KSD; ++p2){
          const float* pp = pDf + ((size_t)p2*NB + b)*NGATE;
          g0 += (double)pp[h];        g1 += (double)pp[1024+h];
          g2 += (double)pp[2048+h];   g3 += (double)pp[3072+h];
        }
        const double cp = dc[b*ARNN + h];
        const double cn = sigd(g1)*cp + sigd(g0)*tanh(g2);
        const double hn = sigd(g3)*tanh(cn);
        dc[b*ARNN+h] = cn; dh[b*ARNN+h] = hn;
      }
    }
  } else {
    if (t < TOUT-1){
      const int b = wg - 2*NB, t1 = t + 1;
      double* pre_next = ws + ((t1 & 1) ? PRE1_OFF : PRE0_OFF);
      for (int m = tid; m < NMEL; m += TPB)
        sb[m] = (double)P.dec[((size_t)b*NMEL + m)*TOUT + (t1-1)];
      __syncthreads();
      uint32_t d1k0, d1k1, d2k0, d2k1;
      tf_block(0u, 42u, 0u, 0u, d1k0, d1k1);
      tf_block(0u, 42u, 0u, 1u, d2k0, d2k1);
      const uint32_t flat = ((uint32_t)(t1*NB + b))*PDIM + tid;
      {
        const float* w = P.Wpre1 + tid*NMEL;
        double s = 0.0;
        for (int m = 0; m < NMEL; ++m) s += sb[m]*(double)w[m];
        double hv = tf_keep_part(d1k0, d1k1, flat) ? s*2.0 : 0.0;
        sb[128 + tid] = fmax(hv, 0.0);
      }
      __syncthreads();
      {
        const float* w = P.Wpre2 + tid*PDIM;
        double s = 0.0;
        for (int m = 0; m < PDIM; ++m) s += sb[128+m]*(double)w[m];
        double pv = tf_keep_part(d2k0, d2k1, flat) ? s*2.0 : 0.0;
        pre_next[(b<<8) + tid] = fmax(pv, 0.0);
      }
    }
  }
}

// ---------------- K3: attention energies (t) + mel/gate (t-1) -------------------------
__global__ __launch_bounds__(TPB) void k3_att(DecParams P, int t)
{
  const int wg = blockIdx.x, tid = threadIdx.x;
  __shared__ double sb[1856];
  double* ws = P.ws;
  double* pmT = ws + PM_OFF;   double* wfc = ws + WFC_OFF;
  double* dh  = ws + DH_OFF;   double* ctx = ws + CTX_OFF;
  double* aw  = ws + AW_OFF;   double* awc = ws + AWC_OFF;
  double* en  = ws + EN_OFF;   double* pq  = ws + PQ_OFF;
  const float* WpgT = (float*)(ws + DBL_END) + WPGT_OFF;

  if (wg < 224){
    if (t < TOUT){
      const int b = wg / 7, tt = wg - b*7;
      const int tbase = tt*64;
      if (tid < ADIM) sb[tid] = pq[b*ADIM + tid];
      for (int i = tid; i < 94; i += TPB){
        int tg = tbase - 15 + i;
        sb[128 + i] = (tg >= 0 && tg < TIN) ? aw[b*TIN + tg] : 0.0;
      }
      for (int i = tid; i < 94; i += TPB){
        int tg = tbase - 15 + i;
        sb[222 + i] = (tg >= 0 && tg < TIN) ? awc[b*TIN + tg] : 0.0;
      }
      __syncthreads();
      const int wv = tid >> 6, lane = tid & 63;
      const int tg = tbase + lane;
      double esum = 0.0;
      if (tg < TIN){
        double w0r[31], w1r[31];
        #pragma unroll
        for (int k = 0; k < 31; ++k){ w0r[k] = sb[128 + lane + k]; w1r[k] = sb[222 + lane + k]; }
        const double* pmrow = pmT + (size_t)b*ADIM*TIN + tg;
        for (int a2 = wv*32; a2 < wv*32 + 32; ++a2){
          const double* wf = wfc + a2*62;
          double cv = 0.0;
          #pragma unroll
          for (int k = 0; k < 31; ++k) cv += wf[k]*w0r[k];
          #pragma unroll
          for (int k = 0; k < 31; ++k) cv += wf[31+k]*w1r[k];
          const double e = sb[a2] + cv + pmrow[(size_t)a2*TIN];
          esum += (double)P.v[a2]*tanh(e);
        }
      }
      sb[640 + wv*64 + lane] = esum;
      __syncthreads();
      if (tid < 64){
        const int tg2 = tbase + tid;
        if (tg2 < TIN){
          double e = sb[640+tid] + sb[704+tid] + sb[768+tid] + sb[832+tid];
          if (P.mask[b*TIN + tg2]) e = -1e9;
          en[b*TIN + tg2] = e;
        }
      }
    }
  } else {
    if (t > 0){
      const int b = wg - 224, ts = t-1;
      for (int i = tid; i < 1536; i += TPB)
        sb[i] = (i < 1024) ? dh[b*ARNN + i] : ctx[b*EDIM + (i-1024)];
      __syncthreads();
      const int o = tid >> 1, hf = tid & 1;
      double s = 0.0;
      if (o <= 80){
        const float* wpt = WpgT + (size_t)(hf*768)*81 + o;
        const double* xr = sb + hf*768;
        for (int m2 = 0; m2 < 768; ++m2) s += (double)wpt[(size_t)m2*81]*xr[m2];
      }
      sb[1600 + tid] = s;
      __syncthreads();
      if (tid <= 80){
        double val = sb[1600 + 2*tid] + sb[1600 + 2*tid + 1];
        if (tid < 80) P.out[MEL_OFF + ((size_t)b*NMEL + tid)*TOUT + ts] = (float)(val + (double)P.bp[tid]);
        else          P.out[GATE_OFF + (size_t)b*TOUT + ts] = (float)(val + (double)P.bg[0]);
      }
    }
  }
}

// ---------------- K4: softmax (redundant x8) + ctx slice on 256 blocks ----------------
__global__ __launch_bounds__(TPB) void k4_ctx(DecParams P, int t)
{
  if (t >= TOUT) return;
  const int wg = blockIdx.x, tid = threadIdx.x;
  __shared__ double sb[1280];
  double* ws = P.ws;
  double* ctx = ws + CTX_OFF;  double* aw  = ws + AW_OFF;  double* awc = ws + AWC_OFF;
  double* en  = ws + EN_OFF;

  const int b = wg >> 3, s = wg & 7;
  double m = -1.0e300;
  for (int i = tid; i < TIN; i += TPB){
    double e = en[b*TIN + i];
    sb[512 + i] = e;
    m = fmax(m, e);
  }
  sb[tid] = m; __syncthreads();
  for (int s2 = TPB/2; s2 > 0; s2 >>= 1){
    if (tid < s2) sb[tid] = fmax(sb[tid], sb[tid+s2]);
    __syncthreads();
  }
  const double mx = sb[0];
  __syncthreads();
  double ssum = 0.0;
  for (int i = tid; i < TIN; i += TPB){
    double u = exp(sb[512+i] - mx);
    sb[512 + i] = u; ssum += u;
  }
  sb[tid] = ssum; __syncthreads();
  for (int s2 = TPB/2; s2 > 0; s2 >>= 1){
    if (tid < s2) sb[tid] += sb[tid+s2];
    __syncthreads();
  }
  const double tot = sb[0];
  __syncthreads();
  for (int i = tid; i < TIN; i += TPB){
    double a2 = sb[512+i] / tot;
    sb[512+i] = a2;
    if (s == 0){
      aw[b*TIN+i] = a2;
      awc[b*TIN+i] += a2;
      P.out[AL_OFF + ((size_t)b*TOUT + t)*TIN + i] = (float)a2;
    }
  }
  __syncthreads();
  {
    const int e2 = s*64 + (tid & 63);
    const int tc = tid >> 6;                     // 0..3 -> t-chunks of 100
    const float* mcol = P.memory + (size_t)b*TIN*EDIM + e2;
    double sacc = 0.0;
    for (int t2 = tc*100; t2 < tc*100 + 100; ++t2)
      sacc += sb[512+t2] * (double)mcol[(size_t)t2*EDIM];
    sb[1024 + tid] = sacc;
    __syncthreads();
    if (tid < 64){
      double v4 = sb[1024+tid] + sb[1088+tid] + sb[1152+tid] + sb[1216+tid];
      ctx[b*EDIM + s*64 + tid] = v4;
    }
  }
}

extern "C" void kernel_launch(void* const* d_in, const int* in_sizes, int n_in,
                              void* d_out, int out_size, void* d_ws, size_t ws_size,
                              hipStream_t stream)
{
  const float* memory = (const float*)d_in[0];
  const float* dec    = (const float*)d_in[1];
  const unsigned char* mask = (const unsigned char*)d_in[2];
  const float* W_pre1 = (const float*)d_in[3];
  const float* W_pre2 = (const float*)d_in[4];
  const float* WihA   = (const float*)d_in[5];
  const float* WhhA   = (const float*)d_in[6];
  const float* bihA   = (const float*)d_in[7];
  const float* bhhA   = (const float*)d_in[8];
  const float* Wq     = (const float*)d_in[9];
  const float* Wm     = (const float*)d_in[10];
  const float* v      = (const float*)d_in[11];
  const float* Wc     = (const float*)d_in[12];
  const float* Wd     = (const float*)d_in[13];
  const float* WihD   = (const float*)d_in[14];
  const float* WhhD   = (const float*)d_in[15];
  const float* bihD   = (const float*)d_in[16];
  const float* bhhD   = (const float*)d_in[17];
  const float* Wp     = (const float*)d_in[18];
  const float* bp     = (const float*)d_in[19];
  const float* Wg     = (const float*)d_in[20];
  const float* bg     = (const float*)d_in[21];

  double* ws = (double*)d_ws;
  float* out = (float*)d_out;

  if (ws_size < WS_BYTES){
    sentinel_kernel<<<1, 1, 0, stream>>>(out, 12345.0f);   // diagnostic: ws too small
    return;
  }

  zero_kernel<<<GRID_WGS, TPB, 0, stream>>>(ws);
  pm_kernel<<<NB*TIN, TPB, 0, stream>>>(memory, Wm, ws + PM_OFF);
  wfc_kernel<<<1, TPB, 0, stream>>>(Wd, Wc, ws + WFC_OFF);
  {
    float* fbase = (float*)(ws + DBL_END);
    wqt_kernel<<<ADIM, TPB, 0, stream>>>(Wq, fbase + WQT_OFF);
    wpgt_kernel<<<64, TPB, 0, stream>>>(Wp, Wg, fbase + WPGT_OFF);
  }

  DecParams P;
  P.memory = memory; P.dec = dec;
  P.Wpre1 = W_pre1; P.Wpre2 = W_pre2;
  P.WihA = WihA; P.WhhA = WhhA; P.bihA = bihA; P.bhhA = bhhA;
  P.Wq = Wq; P.v = v;
  P.WihD = WihD; P.WhhD = WhhD; P.bihD = bihD; P.bhhD = bhhD;
  P.Wp = Wp; P.bp = bp; P.Wg = Wg; P.bg = bg;
  P.mask = mask; P.ws = ws; P.out = out;

  for (int t = 0; t <= TOUT; ++t){
    k1_gemm<<<K1_GRID, TPB, 0, stream>>>(P, t);
    k2_reduce<<<3*NB, TPB, 0, stream>>>(P, t);
    k3_att<<<256, TPB, 0, stream>>>(P, t);
    if (t < TOUT) k4_ctx<<<256, TPB, 0, stream>>>(P, t);
  }
}